// Round 1
// baseline (2190.208 us; speedup 1.0000x reference)
//
#include <hip/hip_runtime.h>

#define N_NODES 100000
#define N_EDGES 3200000
#define D 16
#define L 3

// One thread per edge: deg[dst] += 1
__global__ void deg_kernel(const int* __restrict__ dst, float* __restrict__ deg, int E) {
    int e = blockIdx.x * blockDim.x + threadIdx.x;
    if (e < E) atomicAdd(&deg[dst[e]], 1.0f);
}

// 4 threads per edge: each handles a float4 slice of the D=16 feature row.
// agg[dst] += x[src]
__global__ void scatter_kernel(const int* __restrict__ src, const int* __restrict__ dst,
                               const float* __restrict__ x, float* __restrict__ agg, int E) {
    int t = blockIdx.x * blockDim.x + threadIdx.x;
    int e = t >> 2;
    int q = t & 3;
    if (e >= E) return;
    int s = src[e];
    int d = dst[e];
    const float4 v = *(const float4*)(x + (size_t)s * D + q * 4);
    float* out = agg + (size_t)d * D + q * 4;
    atomicAdd(out + 0, v.x);
    atomicAdd(out + 1, v.y);
    atomicAdd(out + 2, v.z);
    atomicAdd(out + 3, v.w);
}

// One thread per node: xout = (agg/max(deg,1)) @ Wl^T + x @ (Wr+Wlin)^T + (bl+blin)
// Weights staged in LDS; all lanes read the same LDS word -> broadcast, no conflicts.
__global__ void transform_kernel(const float* __restrict__ xin,
                                 const float* __restrict__ agg,
                                 const float* __restrict__ deg,
                                 const float* __restrict__ Wl,
                                 const float* __restrict__ bl,
                                 const float* __restrict__ Wr,
                                 const float* __restrict__ Wlin,
                                 const float* __restrict__ blin,
                                 float* __restrict__ xout, int N) {
    __shared__ float sWl[D * D];
    __shared__ float sWc[D * D];
    __shared__ float sbc[D];
    int tid = threadIdx.x;
    if (tid < D * D) {
        sWl[tid] = Wl[tid];
        sWc[tid] = Wr[tid] + Wlin[tid];
    }
    if (tid < D) sbc[tid] = bl[tid] + blin[tid];
    __syncthreads();

    int n = blockIdx.x * blockDim.x + tid;
    if (n >= N) return;

    float a[D], xv[D];
    float inv = 1.0f / fmaxf(deg[n], 1.0f);
    #pragma unroll
    for (int k = 0; k < D; k += 4) {
        float4 t = *(const float4*)(agg + (size_t)n * D + k);
        a[k] = t.x * inv; a[k + 1] = t.y * inv; a[k + 2] = t.z * inv; a[k + 3] = t.w * inv;
        float4 u = *(const float4*)(xin + (size_t)n * D + k);
        xv[k] = u.x; xv[k + 1] = u.y; xv[k + 2] = u.z; xv[k + 3] = u.w;
    }

    float o[D];
    #pragma unroll
    for (int j = 0; j < D; j++) {
        float acc = sbc[j];
        #pragma unroll
        for (int k = 0; k < D; k++) {
            acc += a[k] * sWl[j * D + k];
            acc += xv[k] * sWc[j * D + k];
        }
        o[j] = acc;
    }
    #pragma unroll
    for (int j = 0; j < D; j += 4) {
        float4 w = make_float4(o[j], o[j + 1], o[j + 2], o[j + 3]);
        *(float4*)(xout + (size_t)n * D + j) = w;
    }
}

extern "C" void kernel_launch(void* const* d_in, const int* in_sizes, int n_in,
                              void* d_out, int out_size, void* d_ws, size_t ws_size,
                              hipStream_t stream) {
    const float* x    = (const float*)d_in[0];
    const int*   ei   = (const int*)d_in[1];   // (2, E) int32: first E = src, next E = dst
    const float* Wl   = (const float*)d_in[2]; // (L, D, D)
    const float* bl   = (const float*)d_in[3]; // (L, D)
    const float* Wr   = (const float*)d_in[4];
    const float* Wlin = (const float*)d_in[5];
    const float* blin = (const float*)d_in[6];
    float* out = (float*)d_out;

    const int* src = ei;
    const int* dst = ei + N_EDGES;

    float* deg  = (float*)d_ws;              // N floats
    float* agg  = deg + N_NODES;             // N*D floats
    float* bufA = agg + (size_t)N_NODES * D; // N*D floats

    // degree (same every layer)
    hipMemsetAsync(deg, 0, N_NODES * sizeof(float), stream);
    deg_kernel<<<(N_EDGES + 255) / 256, 256, 0, stream>>>(dst, deg, N_EDGES);

    const float* cur = x;
    for (int i = 0; i < L; i++) {
        float* nxt = (i == L - 1) ? out : bufA;  // layer1: bufA->bufA in-place (row-local, safe)
        hipMemsetAsync(agg, 0, (size_t)N_NODES * D * sizeof(float), stream);
        scatter_kernel<<<(N_EDGES * 4 + 255) / 256, 256, 0, stream>>>(src, dst, cur, agg, N_EDGES);
        transform_kernel<<<(N_NODES + 255) / 256, 256, 0, stream>>>(
            cur, agg, deg,
            Wl + i * D * D, bl + i * D, Wr + i * D * D, Wlin + i * D * D, blin + i * D,
            nxt, N_NODES);
        cur = nxt;
    }
}

// Round 2
// 661.139 us; speedup vs baseline: 3.3128x; 3.3128x over previous
//
#include <hip/hip_runtime.h>

#define N_NODES 100000
#define N_EDGES 3200000
#define D 16
#define L 3

#define SCAN_BLOCK 256
#define SCAN_CHUNK 1024                                   // 4 elems/thread
#define N_SCAN_BLOCKS ((N_NODES + SCAN_CHUNK - 1) / SCAN_CHUNK)  // 98

// ---- CSR build ----

__global__ void hist_kernel(const int* __restrict__ dst, int* __restrict__ cnt, int E) {
    int e = blockIdx.x * blockDim.x + threadIdx.x;
    if (e < E) atomicAdd(&cnt[dst[e]], 1);
}

// per-block reduce of cnt chunks -> blocksum[b]
__global__ void scan_a(const int* __restrict__ cnt, int* __restrict__ blocksum, int N) {
    __shared__ int s[SCAN_BLOCK];
    int tid = threadIdx.x;
    int base = blockIdx.x * SCAN_CHUNK + tid * 4;
    int sum = 0;
    #pragma unroll
    for (int i = 0; i < 4; i++) { int idx = base + i; if (idx < N) sum += cnt[idx]; }
    s[tid] = sum; __syncthreads();
    for (int off = SCAN_BLOCK / 2; off > 0; off >>= 1) {
        if (tid < off) s[tid] += s[tid + off];
        __syncthreads();
    }
    if (tid == 0) blocksum[blockIdx.x] = s[0];
}

// tiny sequential exclusive scan over block sums (98 elements)
__global__ void scan_b(int* __restrict__ blocksum, int nb) {
    if (threadIdx.x == 0 && blockIdx.x == 0) {
        int acc = 0;
        for (int i = 0; i < nb; i++) { int v = blocksum[i]; blocksum[i] = acc; acc += v; }
    }
}

// per-block exclusive scan + block offset -> rowstart, cursor
__global__ void scan_c(const int* __restrict__ cnt, const int* __restrict__ blocksum,
                       int* __restrict__ rowstart, int* __restrict__ cursor, int N) {
    __shared__ int s[SCAN_BLOCK];
    int tid = threadIdx.x;
    int base = blockIdx.x * SCAN_CHUNK + tid * 4;
    int v[4]; int sum = 0;
    #pragma unroll
    for (int i = 0; i < 4; i++) { int idx = base + i; v[i] = (idx < N) ? cnt[idx] : 0; sum += v[i]; }
    s[tid] = sum; __syncthreads();
    for (int off = 1; off < SCAN_BLOCK; off <<= 1) {       // inclusive Hillis-Steele
        int t = (tid >= off) ? s[tid - off] : 0;
        __syncthreads();
        s[tid] += t;
        __syncthreads();
    }
    int excl = blocksum[blockIdx.x] + s[tid] - sum;        // exclusive prefix of this thread's chunk
    #pragma unroll
    for (int i = 0; i < 4; i++) {
        int idx = base + i;
        if (idx < N) { rowstart[idx] = excl; cursor[idx] = excl; excl += v[i]; }
    }
}

__global__ void build_kernel(const int* __restrict__ src, const int* __restrict__ dst,
                             int* __restrict__ cursor, int* __restrict__ csr_src, int E) {
    int e = blockIdx.x * blockDim.x + threadIdx.x;
    if (e < E) {
        int pos = atomicAdd(&cursor[dst[e]], 1);
        csr_src[pos] = src[e];
    }
}

// ---- fused segmented-mean + transform ----
// 4 lanes per node; lane q owns feature quarter [4q,4q+4).
// out = (agg/max(deg,1)) @ Wl^T + x @ (Wr+Wlin)^T + (bl+blin)
__global__ void agg_transform_kernel(const float* __restrict__ xin,
                                     const int* __restrict__ csr_src,
                                     const int* __restrict__ rowstart,
                                     const int* __restrict__ cnt,
                                     const float* __restrict__ Wl,
                                     const float* __restrict__ bl,
                                     const float* __restrict__ Wr,
                                     const float* __restrict__ Wlin,
                                     const float* __restrict__ blin,
                                     float* __restrict__ xout, int N) {
    __shared__ float sWl[D * D];
    __shared__ float sWc[D * D];
    __shared__ float sbc[D];
    int tid = threadIdx.x;
    if (tid < D * D) {
        sWl[tid] = Wl[tid];
        sWc[tid] = Wr[tid] + Wlin[tid];
    }
    if (tid < D) sbc[tid] = bl[tid] + blin[tid];
    __syncthreads();

    int t = blockIdx.x * blockDim.x + tid;
    int n = t >> 2;
    int q = t & 3;
    if (n >= N) return;

    int start = rowstart[n];
    int deg = cnt[n];
    int end = start + deg;

    float4 acc = make_float4(0.f, 0.f, 0.f, 0.f);
    for (int i = start; i < end; i++) {
        int s = csr_src[i];
        float4 v = *(const float4*)(xin + (size_t)s * D + q * 4);
        acc.x += v.x; acc.y += v.y; acc.z += v.z; acc.w += v.w;
    }
    float inv = 1.0f / fmaxf((float)deg, 1.0f);
    float a[4] = { acc.x * inv, acc.y * inv, acc.z * inv, acc.w * inv };
    float4 xq = *(const float4*)(xin + (size_t)n * D + q * 4);
    float xv[4] = { xq.x, xq.y, xq.z, xq.w };

    float o[4];
    #pragma unroll
    for (int j = 0; j < D; j++) {
        float p = 0.f;
        #pragma unroll
        for (int k = 0; k < 4; k++) {
            int kk = q * 4 + k;
            p += a[k] * sWl[j * D + kk] + xv[k] * sWc[j * D + kk];
        }
        p += __shfl_xor(p, 1, 4);
        p += __shfl_xor(p, 2, 4);
        if ((j >> 2) == q) o[j & 3] = p + sbc[j];
    }
    *(float4*)(xout + (size_t)n * D + q * 4) = make_float4(o[0], o[1], o[2], o[3]);
}

extern "C" void kernel_launch(void* const* d_in, const int* in_sizes, int n_in,
                              void* d_out, int out_size, void* d_ws, size_t ws_size,
                              hipStream_t stream) {
    const float* x    = (const float*)d_in[0];
    const int*   ei   = (const int*)d_in[1];   // (2, E): first E = src, next E = dst
    const float* Wl   = (const float*)d_in[2];
    const float* bl   = (const float*)d_in[3];
    const float* Wr   = (const float*)d_in[4];
    const float* Wlin = (const float*)d_in[5];
    const float* blin = (const float*)d_in[6];
    float* out = (float*)d_out;

    const int* src = ei;
    const int* dst = ei + N_EDGES;

    // workspace layout (16B-aligned chunks)
    char* w = (char*)d_ws;
    int*   csr_src  = (int*)w;                       w += (size_t)N_EDGES * 4;      // 12.8 MB
    float* bufA     = (float*)w;                     w += (size_t)N_NODES * D * 4;  // 6.4 MB
    float* bufB     = (float*)w;                     w += (size_t)N_NODES * D * 4;  // 6.4 MB
    int*   cnt      = (int*)w;                       w += (size_t)N_NODES * 4;
    int*   rowstart = (int*)w;                       w += (size_t)N_NODES * 4;
    int*   cursor   = (int*)w;                       w += (size_t)N_NODES * 4;
    int*   blocksum = (int*)w;                       w += 128 * 4;

    // CSR build (once per call; reused by all 3 layers)
    hipMemsetAsync(cnt, 0, N_NODES * sizeof(int), stream);
    hist_kernel<<<(N_EDGES + 255) / 256, 256, 0, stream>>>(dst, cnt, N_EDGES);
    scan_a<<<N_SCAN_BLOCKS, SCAN_BLOCK, 0, stream>>>(cnt, blocksum, N_NODES);
    scan_b<<<1, 64, 0, stream>>>(blocksum, N_SCAN_BLOCKS);
    scan_c<<<N_SCAN_BLOCKS, SCAN_BLOCK, 0, stream>>>(cnt, blocksum, rowstart, cursor, N_NODES);
    build_kernel<<<(N_EDGES + 255) / 256, 256, 0, stream>>>(src, dst, cursor, csr_src, N_EDGES);

    // layers: x -> bufA -> bufB -> out (no in-place: aggregation reads other rows)
    const float* cur = x;
    float* nxts[L] = { bufA, bufB, out };
    for (int i = 0; i < L; i++) {
        agg_transform_kernel<<<((N_NODES * 4) + 255) / 256, 256, 0, stream>>>(
            cur, csr_src, rowstart, cnt,
            Wl + i * D * D, bl + i * D, Wr + i * D * D, Wlin + i * D * D, blin + i * D,
            nxts[i], N_NODES);
        cur = nxts[i];
    }
}